// Round 4
// baseline (3427.449 us; speedup 1.0000x reference)
//
#include <hip/hip_runtime.h>
#include <math.h>

#define NT 262144
#define NS 512
#define ES 2097152
#define EO 8192
#define NLAYER 4
#define NTILE 4096      // 64-node destination tiles
#define TILE_CAP 1024   // LDS edge-stage chunk (avg tile = 512, +22 sigma safe)

typedef short bf16x8 __attribute__((ext_vector_type(8)));
typedef float f32x16 __attribute__((ext_vector_type(16)));

__device__ inline unsigned short rne_bf16(float f) {
    unsigned int u = __float_as_uint(f);
    u += 0x7FFF + ((u >> 16) & 1);
    return (unsigned short)(u >> 16);
}

// ---------------- tile-bucketed edge build ----------------
__global__ void hist_tile_kernel(const int* __restrict__ dst, int* __restrict__ tcnt) {
    int e = blockIdx.x * 256 + threadIdx.x;
    if (e < ES) atomicAdd(&tcnt[dst[e] >> 6], 1);
}

// one block, 1024 threads, 4 tiles/thread: exclusive scan of tcnt -> bptr, tcur
__global__ void scan_tile_kernel(const int* __restrict__ tcnt, int* __restrict__ bptr,
                                 int* __restrict__ tcur) {
    __shared__ int lds[1024];
    int t = threadIdx.x;
    int4 v = *(const int4*)(tcnt + t * 4);
    int s = v.x + v.y + v.z + v.w;
    lds[t] = s;
    __syncthreads();
    for (int off = 1; off < 1024; off <<= 1) {
        int x = (t >= off) ? lds[t - off] : 0;
        __syncthreads();
        lds[t] += x;
        __syncthreads();
    }
    int excl = lds[t] - s;
    int p0 = excl, p1 = excl + v.x, p2 = p1 + v.y, p3 = p2 + v.z;
    bptr[t * 4 + 0] = p0; tcur[t * 4 + 0] = p0;
    bptr[t * 4 + 1] = p1; tcur[t * 4 + 1] = p1;
    bptr[t * 4 + 2] = p2; tcur[t * 4 + 2] = p2;
    bptr[t * 4 + 3] = p3; tcur[t * 4 + 3] = p3;
    if (t == 1023) bptr[NTILE] = lds[1023];
}

__global__ void scatter_tile_kernel(const int* __restrict__ ei, int* __restrict__ tcur,
                                    unsigned short* __restrict__ ebuf) {
    int e = blockIdx.x * 256 + threadIdx.x;
    if (e < ES) {
        int s = ei[e];
        int d = ei[ES + e];
        int pos = atomicAdd(&tcur[d >> 6], 1);
        ebuf[pos] = (unsigned short)((s & 511) | ((d & 63) << 9));
    }
}

// ---------------- CSR build (small graph, single block) ----------------
__global__ void small_csr_kernel(const int* __restrict__ oei, int* __restrict__ rowptrS,
                                 int* __restrict__ srcsS) {
    __shared__ int sdeg[NS];
    __shared__ int scur[NS];
    int t = threadIdx.x;
    if (t < NS) sdeg[t] = 0;
    __syncthreads();
    for (int e = t; e < EO; e += 1024) atomicAdd(&sdeg[oei[EO + e]], 1);
    __syncthreads();
    int myv = (t < NS) ? sdeg[t] : 0;
    __syncthreads();
    for (int off = 1; off < NS; off <<= 1) {
        int x = (t >= off && t < NS) ? sdeg[t - off] : 0;
        __syncthreads();
        if (t < NS) sdeg[t] += x;
        __syncthreads();
    }
    if (t < NS) {
        int excl = sdeg[t] - myv;
        rowptrS[t] = excl;
        scur[t] = excl;
        if (t == 0) rowptrS[NS] = EO;
    }
    __syncthreads();
    for (int e = t; e < EO; e += 1024) {
        int d = oei[EO + e];
        int pos = atomicAdd(&scur[d], 1);
        srcsS[pos] = oei[e];
    }
}

// ---------------- MFMA gconv (big graph), edge-parallel gather ----------------
// Block = one 64-node tile. XCD swizzle keeps the 8 tiles of a subgraph on one
// XCD (gather window 128 KB -> L2-resident; verified R3: FETCH 234->50 MB).
// Gather: stage u16 edge recs in LDS, waves stream edges, ds_add_f32 into
// padded agg[64][68]. MFMA: A=[agg|h] split-bf16 from LDS/global in-register.
__global__ __launch_bounds__(256, 4) void gconv_mfma_kernel(
    const float* __restrict__ hin, const int* __restrict__ bptr,
    const unsigned short* __restrict__ ebuf,
    const float* __restrict__ Wr, const float* __restrict__ Wt, const float* __restrict__ br,
    float* __restrict__ hout, float* __restrict__ stats)
{
    __shared__ float agg[64 * 68];              // 17.4 KB, +4 pad breaks b128 conflicts
    __shared__ unsigned short erec[TILE_CAP];   // 2 KB

    int p = blockIdx.x;
    int xx = p & 7;
    int q = p >> 3;
    int sub = xx + 8 * (q >> 3);
    int tile = q & 7;
    int T = sub * 8 + tile;
    int nb = T * 64;

    int tid = threadIdx.x;
    int w = tid >> 6;
    int l = tid & 63;

    for (int i = tid; i < 64 * 68; i += 256) agg[i] = 0.f;
    __syncthreads();

    // ---- edge-parallel gather ----
    int e0 = bptr[T], e1 = bptr[T + 1];
    const float* hsub = hin + (size_t)sub * 512 * 64;
    for (int base = e0; base < e1; base += TILE_CAP) {
        int cnt = min(e1 - base, TILE_CAP);
        for (int i = tid; i < cnt; i += 256) erec[i] = ebuf[base + i];
        __syncthreads();
        for (int i = w; i < cnt; i += 4) {
            unsigned int rec = erec[i];
            int sloc = rec & 511;
            int dloc = rec >> 9;
            float v = hsub[sloc * 64 + l];
            atomicAdd(&agg[dloc * 68 + l], v);
        }
        __syncthreads();
    }

    // ---- B fragments (after gather to keep gather-phase VGPR low) ----
    int nt = w >> 1;
    int ct = w & 1;
    int n_out = ct * 32 + (l & 31);
    int kh = l >> 5;   // 0/1 -> +0/+8 within 16-wide k-chunk

    bf16x8 Bh[8], Bl[8];
    #pragma unroll
    for (int kc = 0; kc < 8; kc++) {
        int kbase = kc * 16 + kh * 8;
        const float* wsrc = (kbase < 64) ? (Wr + n_out * 64 + kbase)
                                         : (Wt + n_out * 64 + (kbase - 64));
        float4 u0 = *(const float4*)(wsrc);
        float4 u1 = *(const float4*)(wsrc + 4);
        float vv[8] = {u0.x, u0.y, u0.z, u0.w, u1.x, u1.y, u1.z, u1.w};
        #pragma unroll
        for (int j = 0; j < 8; j++) {
            unsigned short hi = rne_bf16(vv[j]);
            float hif = __uint_as_float((unsigned int)hi << 16);
            Bh[kc][j] = (short)hi;
            Bl[kc][j] = (short)rne_bf16(vv[j] - hif);
        }
    }
    float bias = br[n_out];

    // ---- MFMA: A = [agg | h], 3 MFMAs per 16-chunk (hh, lh, hl) ----
    f32x16 acc;
    #pragma unroll
    for (int j = 0; j < 16; j++) acc[j] = bias;

    int row = nt * 32 + (l & 31);
    const float* hrow = hin + (size_t)(nb + row) * 64;
    #pragma unroll
    for (int kc = 0; kc < 8; kc++) {
        int k0 = kc * 16 + kh * 8;
        float vv[8];
        if (kc < 4) {
            float4 a0 = *(const float4*)(agg + row * 68 + k0);
            float4 a1 = *(const float4*)(agg + row * 68 + k0 + 4);
            vv[0]=a0.x; vv[1]=a0.y; vv[2]=a0.z; vv[3]=a0.w;
            vv[4]=a1.x; vv[5]=a1.y; vv[6]=a1.z; vv[7]=a1.w;
        } else {
            float4 a0 = *(const float4*)(hrow + k0 - 64);
            float4 a1 = *(const float4*)(hrow + k0 - 60);
            vv[0]=a0.x; vv[1]=a0.y; vv[2]=a0.z; vv[3]=a0.w;
            vv[4]=a1.x; vv[5]=a1.y; vv[6]=a1.z; vv[7]=a1.w;
        }
        bf16x8 ah, al;
        #pragma unroll
        for (int j = 0; j < 8; j++) {
            unsigned short hi = rne_bf16(vv[j]);
            float hif = __uint_as_float((unsigned int)hi << 16);
            ah[j] = (short)hi;
            al[j] = (short)rne_bf16(vv[j] - hif);
        }
        acc = __builtin_amdgcn_mfma_f32_32x32x16_bf16(ah, Bh[kc], acc, 0, 0, 0);
        acc = __builtin_amdgcn_mfma_f32_32x32x16_bf16(al, Bh[kc], acc, 0, 0, 0);
        acc = __builtin_amdgcn_mfma_f32_32x32x16_bf16(ah, Bl[kc], acc, 0, 0, 0);
    }

    // ---- epilogue: store h1 + BN stats ----
    float s = 0.f, qv = 0.f;
    #pragma unroll
    for (int j = 0; j < 16; j++) {
        int crow = (j & 3) + 8 * (j >> 2) + 4 * (l >> 5);
        int node = nb + nt * 32 + crow;
        float v = acc[j];
        hout[node * 64 + n_out] = v;
        s += v;
        qv += v * v;
    }
    s += __shfl_xor(s, 32, 64);
    qv += __shfl_xor(qv, 32, 64);
    int rep = p & 31;
    if ((l & 32) == 0) {
        atomicAdd(&stats[rep * 128 + n_out], s);
        atomicAdd(&stats[rep * 128 + 64 + n_out], qv);
    }
}

// ---------------- VALU gconv (512-node small graph) ----------
__global__ __launch_bounds__(512, 6) void gconv_kernel(
    const float* __restrict__ hin, const int* __restrict__ rowptr, const int* __restrict__ srcs,
    const float* __restrict__ Wr, const float* __restrict__ Wt, const float* __restrict__ br,
    float* __restrict__ hout, float* __restrict__ stats)
{
    __shared__ float wrt[4096];
    __shared__ float wtt[4096];
    __shared__ float4 aggT[8][64];
    __shared__ float4 hT[8][64];
    __shared__ float sbuf[8][64];
    __shared__ float qbuf[8][64];
    __shared__ float brs[64];

    int tid = threadIdx.x;
    for (int idx = tid; idx < 4096; idx += 512) {
        int cc = idx >> 6, kk = idx & 63;
        wrt[kk * 64 + ((kk + cc) & 63)] = Wr[idx];
        wtt[kk * 64 + ((kk + cc) & 63)] = Wt[idx];
    }
    if (tid < 64) brs[tid] = br[tid];
    __syncthreads();

    int w = tid >> 6;
    int c = tid & 63;
    int node0 = (blockIdx.x * 8 + w) * 4;

    float* aggp = (float*)&aggT[w][0];
    float* hp   = (float*)&hT[w][0];
    #pragma unroll
    for (int r = 0; r < 4; r++) {
        int node = node0 + r;
        hp[c * 4 + r] = hin[node * 64 + c];
        int e0 = rowptr[node], e1 = rowptr[node + 1];
        float a = 0.f;
        int e = e0;
        for (; e + 4 <= e1; e += 4) {
            int s0 = srcs[e], s1 = srcs[e + 1], s2 = srcs[e + 2], s3 = srcs[e + 3];
            float v0 = hin[s0 * 64 + c];
            float v1 = hin[s1 * 64 + c];
            float v2 = hin[s2 * 64 + c];
            float v3 = hin[s3 * 64 + c];
            a += (v0 + v1) + (v2 + v3);
        }
        for (; e < e1; e++) a += hin[srcs[e] * 64 + c];
        aggp[c * 4 + r] = a;
    }

    float o0 = brs[c], o1 = o0, o2 = o0, o3 = o0;
    #pragma unroll 8
    for (int k = 0; k < 64; k++) {
        float wr = wrt[k * 64 + ((k + c) & 63)];
        float wt = wtt[k * 64 + ((k + c) & 63)];
        float4 av = aggT[w][k];
        float4 hv = hT[w][k];
        o0 += wr * av.x + wt * hv.x;
        o1 += wr * av.y + wt * hv.y;
        o2 += wr * av.z + wt * hv.z;
        o3 += wr * av.w + wt * hv.w;
    }
    hout[(node0 + 0) * 64 + c] = o0;
    hout[(node0 + 1) * 64 + c] = o1;
    hout[(node0 + 2) * 64 + c] = o2;
    hout[(node0 + 3) * 64 + c] = o3;

    sbuf[w][c] = (o0 + o1) + (o2 + o3);
    qbuf[w][c] = (o0 * o0 + o1 * o1) + (o2 * o2 + o3 * o3);
    __syncthreads();
    int rep = blockIdx.x & 31;
    if (w == 0) {
        float s = 0.f;
        #pragma unroll
        for (int ww = 0; ww < 8; ww++) s += sbuf[ww][c];
        atomicAdd(&stats[rep * 128 + c], s);
    } else if (w == 1) {
        float q = 0.f;
        #pragma unroll
        for (int ww = 0; ww < 8; ww++) q += qbuf[ww][c];
        atomicAdd(&stats[rep * 128 + 64 + c], q);
    }
}

// ---------------- subgraph mean (only for the initial x) ----------------
__global__ void smean_kernel(const float* __restrict__ hin, float* __restrict__ xsum) {
    __shared__ float red[16][64];
    int t = threadIdx.x;
    int w = t >> 6, c = t & 63;
    int n = blockIdx.x;
    int base = n * 64 + c;
    float s = 0.f;
    #pragma unroll 8
    for (int j = 0; j < 32; j++) {
        int si = w * 32 + j;
        s += hin[si * 32768 + base];
    }
    red[w][c] = s;
    __syncthreads();
    if (w == 0) {
        float tot = 0.f;
        #pragma unroll
        for (int ww = 0; ww < 16; ww++) tot += red[ww][c];
        xsum[base] = tot * (1.f / 512.f);
    }
}

// ---------------- fold BN stats into per-column scale/shift ----------------
__global__ void finalize_kernel(const float* __restrict__ stB, const float* __restrict__ stS,
                                const float* __restrict__ gB, const float* __restrict__ bB,
                                const float* __restrict__ gS, const float* __restrict__ bS,
                                float* __restrict__ bnp) {
    int c = threadIdx.x;
    float sb = 0.f, qb = 0.f, ss = 0.f, qs = 0.f;
    for (int r = 0; r < 32; r++) {
        sb += stB[r * 128 + c];
        qb += stB[r * 128 + 64 + c];
        ss += stS[r * 128 + c];
        qs += stS[r * 128 + 64 + c];
    }
    float muB = sb * (1.f / 262144.f);
    float varB = qb * (1.f / 262144.f) - muB * muB;
    float scB = gB[c] * rsqrtf(varB + 1e-5f);
    bnp[c] = scB;
    bnp[64 + c] = bB[c] - muB * scB;
    float muS = ss * (1.f / 512.f);
    float varS = qs * (1.f / 512.f) - muS * muS;
    float scS = gS[c] * rsqrtf(varS + 1e-5f);
    bnp[128 + c] = scS;
    bnp[192 + c] = bS[c] - muS * scS;
}

// ---------------- h = relu(bn(h1)+bn(h2)[n]) fused with next-layer smean ----
__global__ __launch_bounds__(1024) void combine_smean_kernel(
    const float* __restrict__ h1, const float* __restrict__ h2,
    const float* __restrict__ bnp, float* __restrict__ hout, float* __restrict__ xsum)
{
    __shared__ float red[16][64];
    int t = threadIdx.x;
    int w = t >> 6;
    int l = t & 63;
    int c4 = (l & 15) * 4;
    int r = l >> 4;
    int n = blockIdx.x;

    float4 sB = *(const float4*)(bnp + c4);
    float4 hB = *(const float4*)(bnp + 64 + c4);
    float4 sS = *(const float4*)(bnp + 128 + c4);
    float4 hS = *(const float4*)(bnp + 192 + c4);
    float4 b2 = *(const float4*)(h2 + n * 64 + c4);
    float bx = b2.x * sS.x + hS.x;
    float by = b2.y * sS.y + hS.y;
    float bz = b2.z * sS.z + hS.z;
    float bw = b2.w * sS.w + hS.w;

    float4 acc = make_float4(0.f, 0.f, 0.f, 0.f);
    #pragma unroll
    for (int j = 0; j < 8; j++) {
        int si = w * 32 + j * 4 + r;
        size_t base = (size_t)(si * 512 + n) * 64 + c4;
        float4 a = *(const float4*)(h1 + base);
        float4 v;
        v.x = fmaxf(a.x * sB.x + hB.x + bx, 0.f);
        v.y = fmaxf(a.y * sB.y + hB.y + by, 0.f);
        v.z = fmaxf(a.z * sB.z + hB.z + bz, 0.f);
        v.w = fmaxf(a.w * sB.w + hB.w + bw, 0.f);
        *(float4*)(hout + base) = v;
        acc.x += v.x; acc.y += v.y; acc.z += v.z; acc.w += v.w;
    }
    acc.x += __shfl_xor(acc.x, 16, 64); acc.y += __shfl_xor(acc.y, 16, 64);
    acc.z += __shfl_xor(acc.z, 16, 64); acc.w += __shfl_xor(acc.w, 16, 64);
    acc.x += __shfl_xor(acc.x, 32, 64); acc.y += __shfl_xor(acc.y, 32, 64);
    acc.z += __shfl_xor(acc.z, 32, 64); acc.w += __shfl_xor(acc.w, 32, 64);
    if (l < 16) {
        red[w][c4 + 0] = acc.x;
        red[w][c4 + 1] = acc.y;
        red[w][c4 + 2] = acc.z;
        red[w][c4 + 3] = acc.w;
    }
    __syncthreads();
    if (t < 64) {
        float tot = 0.f;
        #pragma unroll
        for (int ww = 0; ww < 16; ww++) tot += red[ww][t];
        xsum[n * 64 + t] = tot * (1.f / 512.f);
    }
}

// ---------------- head ----------------
__global__ void head_kernel(const float* __restrict__ xs, const float* __restrict__ W1,
                            const float* __restrict__ b1, const float* __restrict__ W2,
                            const float* __restrict__ b2, float* __restrict__ out) {
    __shared__ float z[64];
    __shared__ float hid[128];
    int t = threadIdx.x;
    int n = blockIdx.x;
    if (t < 64) {
        float v = xs[n * 64 + t];
        float m = v;
        for (int off = 32; off >= 1; off >>= 1) m = fmaxf(m, __shfl_xor(m, off, 64));
        float e = expf(v - m);
        float s = e;
        for (int off = 32; off >= 1; off >>= 1) s += __shfl_xor(s, off, 64);
        z[t] = v - m - logf(s);
    }
    __syncthreads();
    {
        float acc = b1[t];
        const float* wrow = W1 + t * 64;
        #pragma unroll 8
        for (int k = 0; k < 64; k++) acc += z[k] * wrow[k];
        hid[t] = fmaxf(acc, 0.f);
    }
    __syncthreads();
    if (t < 10) {
        float o = b2[t];
        const float* wrow = W2 + t * 128;
        #pragma unroll 8
        for (int j = 0; j < 128; j++) o += hid[j] * wrow[j];
        out[n * 10 + t] = o;
    }
}

extern "C" void kernel_launch(void* const* d_in, const int* in_sizes, int n_in,
                              void* d_out, int out_size, void* d_ws, size_t ws_size,
                              hipStream_t stream) {
    const float* x       = (const float*)d_in[0];
    const float* Wrel    = (const float*)d_in[1];
    const float* brel    = (const float*)d_in[2];
    const float* Wroot   = (const float*)d_in[3];
    const float* bn_g    = (const float*)d_in[4];
    const float* bn_b    = (const float*)d_in[5];
    const float* Wrel_s  = (const float*)d_in[6];
    const float* brel_s  = (const float*)d_in[7];
    const float* Wroot_s = (const float*)d_in[8];
    const float* bns_g   = (const float*)d_in[9];
    const float* bns_b   = (const float*)d_in[10];
    const float* W1      = (const float*)d_in[11];
    const float* b1      = (const float*)d_in[12];
    const float* W2      = (const float*)d_in[13];
    const float* b2      = (const float*)d_in[14];
    const int* ei        = (const int*)d_in[15];
    const int* oei       = (const int*)d_in[16];
    float* out = (float*)d_out;

    char* ws = (char*)d_ws;
    size_t off = 0;
    auto alloc = [&](size_t bytes) -> void* {
        void* p = ws + off;
        off = (off + bytes + 255) & ~(size_t)255;
        return p;
    };
    float* h     = (float*)alloc((size_t)NT * 64 * 4);
    float* h1    = (float*)alloc((size_t)NT * 64 * 4);
    float* xsum  = (float*)alloc(NS * 64 * 4);
    float* h2    = (float*)alloc(NS * 64 * 4);
    float* stats = (float*)alloc(NLAYER * 2 * 4096 * 4);
    float* bnp   = (float*)alloc(256 * 4);
    int* tcnt    = (int*)alloc(NTILE * 4);
    int* bptr    = (int*)alloc((NTILE + 1) * 4);
    int* tcur    = (int*)alloc(NTILE * 4);
    unsigned short* ebuf = (unsigned short*)alloc((size_t)ES * 2);
    int* rowptrS = (int*)alloc(513 * 4);
    int* srcsS   = (int*)alloc(EO * 4);
    (void)ws_size; (void)in_sizes; (void)n_in; (void)out_size;

    hipMemsetAsync(tcnt, 0, NTILE * 4, stream);
    hipMemsetAsync(stats, 0, (size_t)NLAYER * 2 * 4096 * 4, stream);

    hist_tile_kernel<<<ES / 256, 256, 0, stream>>>(ei + ES, tcnt);
    scan_tile_kernel<<<1, 1024, 0, stream>>>(tcnt, bptr, tcur);
    scatter_tile_kernel<<<ES / 256, 256, 0, stream>>>(ei, tcur, ebuf);
    small_csr_kernel<<<1, 1024, 0, stream>>>(oei, rowptrS, srcsS);

    smean_kernel<<<NS, 1024, 0, stream>>>(x, xsum);   // xsum of layer-0 input

    for (int i = 0; i < NLAYER; i++) {
        const float* hin = (i == 0) ? x : h;
        float* stB = stats + i * 8192;
        float* stS = stB + 4096;
        gconv_mfma_kernel<<<NTILE, 256, 0, stream>>>(hin, bptr, ebuf,
            Wrel + i * 4096, Wroot + i * 4096, brel + i * 64, h1, stB);
        gconv_kernel<<<NS / 32, 512, 0, stream>>>(xsum, rowptrS, srcsS,
            Wrel_s + i * 4096, Wroot_s + i * 4096, brel_s + i * 64, h2, stS);
        finalize_kernel<<<1, 64, 0, stream>>>(stB, stS, bn_g + i * 64, bn_b + i * 64,
                                              bns_g + i * 64, bns_b + i * 64, bnp);
        combine_smean_kernel<<<NS, 1024, 0, stream>>>(h1, h2, bnp, h, xsum);
    }
    head_kernel<<<NS, 128, 0, stream>>>(xsum, W1, b1, W2, b2, out);
}

// Round 5
// 994.920 us; speedup vs baseline: 3.4449x; 3.4449x over previous
//
#include <hip/hip_runtime.h>
#include <math.h>

#define NT 262144
#define NS 512
#define ES 2097152
#define EO 8192
#define NLAYER 4
#define NB 16384        // dst>>4 buckets: tile(6b-of-node) x quarter
#define CHUNK 256       // per-wave LDS edge-stage chunk

typedef short bf16x8 __attribute__((ext_vector_type(8)));
typedef float f32x16 __attribute__((ext_vector_type(16)));

__device__ inline unsigned short rne_bf16(float f) {
    unsigned int u = __float_as_uint(f);
    u += 0x7FFF + ((u >> 16) & 1);
    return (unsigned short)(u >> 16);
}

// ---------------- bucketed edge build: bucket id = dst >> 4 ----------------
__global__ void hist_bucket_kernel(const int* __restrict__ dst, int* __restrict__ cnt) {
    int e = blockIdx.x * 256 + threadIdx.x;
    if (e < ES) atomicAdd(&cnt[dst[e] >> 4], 1);
}

// one block, 1024 threads, 16 buckets/thread
__global__ void scan_bucket_kernel(const int* __restrict__ cnt, int* __restrict__ bptr,
                                   int* __restrict__ cur) {
    __shared__ int lds[1024];
    int t = threadIdx.x;
    int4 v0 = ((const int4*)cnt)[t * 4 + 0];
    int4 v1 = ((const int4*)cnt)[t * 4 + 1];
    int4 v2 = ((const int4*)cnt)[t * 4 + 2];
    int4 v3 = ((const int4*)cnt)[t * 4 + 3];
    int vals[16] = {v0.x, v0.y, v0.z, v0.w, v1.x, v1.y, v1.z, v1.w,
                    v2.x, v2.y, v2.z, v2.w, v3.x, v3.y, v3.z, v3.w};
    int s = 0;
    #pragma unroll
    for (int j = 0; j < 16; j++) s += vals[j];
    lds[t] = s;
    __syncthreads();
    for (int off = 1; off < 1024; off <<= 1) {
        int x = (t >= off) ? lds[t - off] : 0;
        __syncthreads();
        lds[t] += x;
        __syncthreads();
    }
    int p = lds[t] - s;
    #pragma unroll
    for (int j = 0; j < 16; j++) {
        bptr[t * 16 + j] = p;
        cur[t * 16 + j] = p;
        p += vals[j];
    }
    if (t == 1023) bptr[NB] = lds[1023];
}

__global__ void scatter_bucket_kernel(const int* __restrict__ ei, int* __restrict__ cur,
                                      unsigned short* __restrict__ ebuf) {
    int e = blockIdx.x * 256 + threadIdx.x;
    if (e < ES) {
        int s = ei[e];
        int d = ei[ES + e];
        int pos = atomicAdd(&cur[d >> 4], 1);
        ebuf[pos] = (unsigned short)((s & 511) | ((d & 63) << 9));
    }
}

// ---------------- CSR build (small graph, single block) ----------------
__global__ void small_csr_kernel(const int* __restrict__ oei, int* __restrict__ rowptrS,
                                 int* __restrict__ srcsS) {
    __shared__ int sdeg[NS];
    __shared__ int scur[NS];
    int t = threadIdx.x;
    if (t < NS) sdeg[t] = 0;
    __syncthreads();
    for (int e = t; e < EO; e += 1024) atomicAdd(&sdeg[oei[EO + e]], 1);
    __syncthreads();
    int myv = (t < NS) ? sdeg[t] : 0;
    __syncthreads();
    for (int off = 1; off < NS; off <<= 1) {
        int x = (t >= off && t < NS) ? sdeg[t - off] : 0;
        __syncthreads();
        if (t < NS) sdeg[t] += x;
        __syncthreads();
    }
    if (t < NS) {
        int excl = sdeg[t] - myv;
        rowptrS[t] = excl;
        scur[t] = excl;
        if (t == 0) rowptrS[NS] = EO;
    }
    __syncthreads();
    for (int e = t; e < EO; e += 1024) {
        int d = oei[EO + e];
        int pos = atomicAdd(&scur[d], 1);
        srcsS[pos] = oei[e];
    }
}

// ---------------- MFMA gconv (big graph), wave-owned edge-parallel gather ----
// Block = one 64-node tile; XCD swizzle keeps a subgraph's 8 tiles on one XCD
// (gather L2-resident, verified R3). Wave w owns dst rows [w*16,w*16+16) ==
// bucket T*4+w, so agg RMW needs NO atomics (DS ops per-wave are in-order).
__global__ __launch_bounds__(256, 4) void gconv_mfma_kernel(
    const float* __restrict__ hin, const int* __restrict__ bptr,
    const unsigned short* __restrict__ ebuf,
    const float* __restrict__ Wr, const float* __restrict__ Wt, const float* __restrict__ br,
    float* __restrict__ hout, float* __restrict__ stats)
{
    __shared__ float agg[64 * 68];                 // 17.4 KB
    __shared__ unsigned short erec[4 * CHUNK];     // 2 KB, per-wave chunks

    int p = blockIdx.x;
    int xx = p & 7;
    int q = p >> 3;
    int sub = xx + 8 * (q >> 3);
    int tile = q & 7;
    int T = sub * 8 + tile;
    int nb = T * 64;

    int tid = threadIdx.x;
    int w = tid >> 6;
    int l = tid & 63;

    for (int i = tid; i < 64 * 68; i += 256) agg[i] = 0.f;
    __syncthreads();

    // ---- gather: wave w streams bucket T*4+w into its own 16 agg rows ----
    int B = T * 4 + w;
    int q0 = bptr[B], q1 = bptr[B + 1];
    const float* hsub = hin + (size_t)sub * 512 * 64;
    unsigned short* myrec = erec + w * CHUNK;
    float* aggw = agg + l;
    for (int base = q0; base < q1; base += CHUNK) {
        int cnt = min(q1 - base, CHUNK);
        for (int i = l; i < cnt; i += 64) myrec[i] = ebuf[base + i];
        __builtin_amdgcn_wave_barrier();
        int j = 0;
        for (; j + 4 <= cnt; j += 4) {
            uint2 rr = *(const uint2*)(myrec + j);   // uniform ds_read_b64 broadcast
            unsigned r0 = rr.x & 0xffffu, r1 = rr.x >> 16;
            unsigned r2 = rr.y & 0xffffu, r3 = rr.y >> 16;
            float v0 = hsub[(r0 & 511) * 64 + l];
            float v1 = hsub[(r1 & 511) * 64 + l];
            float v2 = hsub[(r2 & 511) * 64 + l];
            float v3 = hsub[(r3 & 511) * 64 + l];
            aggw[(r0 >> 9) * 68] += v0;
            aggw[(r1 >> 9) * 68] += v1;
            aggw[(r2 >> 9) * 68] += v2;
            aggw[(r3 >> 9) * 68] += v3;
        }
        for (; j < cnt; j++) {
            unsigned rec = myrec[j];
            float v = hsub[(rec & 511) * 64 + l];
            aggw[(rec >> 9) * 68] += v;
        }
        __builtin_amdgcn_wave_barrier();
    }

    // ---- B fragments ----
    int nt = w >> 1;
    int ct = w & 1;
    int n_out = ct * 32 + (l & 31);
    int kh = l >> 5;

    bf16x8 Bh[8], Bl[8];
    #pragma unroll
    for (int kc = 0; kc < 8; kc++) {
        int kbase = kc * 16 + kh * 8;
        const float* wsrc = (kbase < 64) ? (Wr + n_out * 64 + kbase)
                                         : (Wt + n_out * 64 + (kbase - 64));
        float4 u0 = *(const float4*)(wsrc);
        float4 u1 = *(const float4*)(wsrc + 4);
        float vv[8] = {u0.x, u0.y, u0.z, u0.w, u1.x, u1.y, u1.z, u1.w};
        #pragma unroll
        for (int j = 0; j < 8; j++) {
            unsigned short hi = rne_bf16(vv[j]);
            float hif = __uint_as_float((unsigned int)hi << 16);
            Bh[kc][j] = (short)hi;
            Bl[kc][j] = (short)rne_bf16(vv[j] - hif);
        }
    }
    float bias = br[n_out];
    __syncthreads();

    // ---- MFMA: A = [agg | h], 3 MFMAs per 16-chunk (hh, lh, hl) ----
    f32x16 acc;
    #pragma unroll
    for (int j = 0; j < 16; j++) acc[j] = bias;

    int row = nt * 32 + (l & 31);
    const float* hrow = hin + (size_t)(nb + row) * 64;
    #pragma unroll
    for (int kc = 0; kc < 8; kc++) {
        int k0 = kc * 16 + kh * 8;
        float vv[8];
        if (kc < 4) {
            float4 a0 = *(const float4*)(agg + row * 68 + k0);
            float4 a1 = *(const float4*)(agg + row * 68 + k0 + 4);
            vv[0]=a0.x; vv[1]=a0.y; vv[2]=a0.z; vv[3]=a0.w;
            vv[4]=a1.x; vv[5]=a1.y; vv[6]=a1.z; vv[7]=a1.w;
        } else {
            float4 a0 = *(const float4*)(hrow + k0 - 64);
            float4 a1 = *(const float4*)(hrow + k0 - 60);
            vv[0]=a0.x; vv[1]=a0.y; vv[2]=a0.z; vv[3]=a0.w;
            vv[4]=a1.x; vv[5]=a1.y; vv[6]=a1.z; vv[7]=a1.w;
        }
        bf16x8 ah, al;
        #pragma unroll
        for (int j = 0; j < 8; j++) {
            unsigned short hi = rne_bf16(vv[j]);
            float hif = __uint_as_float((unsigned int)hi << 16);
            ah[j] = (short)hi;
            al[j] = (short)rne_bf16(vv[j] - hif);
        }
        acc = __builtin_amdgcn_mfma_f32_32x32x16_bf16(ah, Bh[kc], acc, 0, 0, 0);
        acc = __builtin_amdgcn_mfma_f32_32x32x16_bf16(al, Bh[kc], acc, 0, 0, 0);
        acc = __builtin_amdgcn_mfma_f32_32x32x16_bf16(ah, Bl[kc], acc, 0, 0, 0);
    }

    // ---- epilogue: store h1 + BN stats ----
    float s = 0.f, qv = 0.f;
    #pragma unroll
    for (int j = 0; j < 16; j++) {
        int crow = (j & 3) + 8 * (j >> 2) + 4 * (l >> 5);
        int node = nb + nt * 32 + crow;
        float v = acc[j];
        hout[node * 64 + n_out] = v;
        s += v;
        qv += v * v;
    }
    s += __shfl_xor(s, 32, 64);
    qv += __shfl_xor(qv, 32, 64);
    int rep = p & 31;
    if ((l & 32) == 0) {
        atomicAdd(&stats[rep * 128 + n_out], s);
        atomicAdd(&stats[rep * 128 + 64 + n_out], qv);
    }
}

// ---------------- VALU gconv (512-node small graph) ----------
__global__ __launch_bounds__(512, 6) void gconv_kernel(
    const float* __restrict__ hin, const int* __restrict__ rowptr, const int* __restrict__ srcs,
    const float* __restrict__ Wr, const float* __restrict__ Wt, const float* __restrict__ br,
    float* __restrict__ hout, float* __restrict__ stats)
{
    __shared__ float wrt[4096];
    __shared__ float wtt[4096];
    __shared__ float4 aggT[8][64];
    __shared__ float4 hT[8][64];
    __shared__ float sbuf[8][64];
    __shared__ float qbuf[8][64];
    __shared__ float brs[64];

    int tid = threadIdx.x;
    for (int idx = tid; idx < 4096; idx += 512) {
        int cc = idx >> 6, kk = idx & 63;
        wrt[kk * 64 + ((kk + cc) & 63)] = Wr[idx];
        wtt[kk * 64 + ((kk + cc) & 63)] = Wt[idx];
    }
    if (tid < 64) brs[tid] = br[tid];
    __syncthreads();

    int w = tid >> 6;
    int c = tid & 63;
    int node0 = (blockIdx.x * 8 + w) * 4;

    float* aggp = (float*)&aggT[w][0];
    float* hp   = (float*)&hT[w][0];
    #pragma unroll
    for (int r = 0; r < 4; r++) {
        int node = node0 + r;
        hp[c * 4 + r] = hin[node * 64 + c];
        int e0 = rowptr[node], e1 = rowptr[node + 1];
        float a = 0.f;
        int e = e0;
        for (; e + 4 <= e1; e += 4) {
            int s0 = srcs[e], s1 = srcs[e + 1], s2 = srcs[e + 2], s3 = srcs[e + 3];
            float v0 = hin[s0 * 64 + c];
            float v1 = hin[s1 * 64 + c];
            float v2 = hin[s2 * 64 + c];
            float v3 = hin[s3 * 64 + c];
            a += (v0 + v1) + (v2 + v3);
        }
        for (; e < e1; e++) a += hin[srcs[e] * 64 + c];
        aggp[c * 4 + r] = a;
    }

    float o0 = brs[c], o1 = o0, o2 = o0, o3 = o0;
    #pragma unroll 8
    for (int k = 0; k < 64; k++) {
        float wr = wrt[k * 64 + ((k + c) & 63)];
        float wt = wtt[k * 64 + ((k + c) & 63)];
        float4 av = aggT[w][k];
        float4 hv = hT[w][k];
        o0 += wr * av.x + wt * hv.x;
        o1 += wr * av.y + wt * hv.y;
        o2 += wr * av.z + wt * hv.z;
        o3 += wr * av.w + wt * hv.w;
    }
    hout[(node0 + 0) * 64 + c] = o0;
    hout[(node0 + 1) * 64 + c] = o1;
    hout[(node0 + 2) * 64 + c] = o2;
    hout[(node0 + 3) * 64 + c] = o3;

    sbuf[w][c] = (o0 + o1) + (o2 + o3);
    qbuf[w][c] = (o0 * o0 + o1 * o1) + (o2 * o2 + o3 * o3);
    __syncthreads();
    int rep = blockIdx.x & 31;
    if (w == 0) {
        float s = 0.f;
        #pragma unroll
        for (int ww = 0; ww < 8; ww++) s += sbuf[ww][c];
        atomicAdd(&stats[rep * 128 + c], s);
    } else if (w == 1) {
        float q = 0.f;
        #pragma unroll
        for (int ww = 0; ww < 8; ww++) q += qbuf[ww][c];
        atomicAdd(&stats[rep * 128 + 64 + c], q);
    }
}

// ---------------- subgraph mean (only for the initial x) ----------------
__global__ void smean_kernel(const float* __restrict__ hin, float* __restrict__ xsum) {
    __shared__ float red[16][64];
    int t = threadIdx.x;
    int w = t >> 6, c = t & 63;
    int n = blockIdx.x;
    int base = n * 64 + c;
    float s = 0.f;
    #pragma unroll 8
    for (int j = 0; j < 32; j++) {
        int si = w * 32 + j;
        s += hin[si * 32768 + base];
    }
    red[w][c] = s;
    __syncthreads();
    if (w == 0) {
        float tot = 0.f;
        #pragma unroll
        for (int ww = 0; ww < 16; ww++) tot += red[ww][c];
        xsum[base] = tot * (1.f / 512.f);
    }
}

// ---------------- fold BN stats into per-column scale/shift ----------------
__global__ void finalize_kernel(const float* __restrict__ stB, const float* __restrict__ stS,
                                const float* __restrict__ gB, const float* __restrict__ bB,
                                const float* __restrict__ gS, const float* __restrict__ bS,
                                float* __restrict__ bnp) {
    int c = threadIdx.x;
    float sb = 0.f, qb = 0.f, ss = 0.f, qs = 0.f;
    for (int r = 0; r < 32; r++) {
        sb += stB[r * 128 + c];
        qb += stB[r * 128 + 64 + c];
        ss += stS[r * 128 + c];
        qs += stS[r * 128 + 64 + c];
    }
    float muB = sb * (1.f / 262144.f);
    float varB = qb * (1.f / 262144.f) - muB * muB;
    float scB = gB[c] * rsqrtf(varB + 1e-5f);
    bnp[c] = scB;
    bnp[64 + c] = bB[c] - muB * scB;
    float muS = ss * (1.f / 512.f);
    float varS = qs * (1.f / 512.f) - muS * muS;
    float scS = gS[c] * rsqrtf(varS + 1e-5f);
    bnp[128 + c] = scS;
    bnp[192 + c] = bS[c] - muS * scS;
}

// ---------------- h = relu(bn(h1)+bn(h2)[n]) fused with next-layer smean ----
__global__ __launch_bounds__(1024) void combine_smean_kernel(
    const float* __restrict__ h1, const float* __restrict__ h2,
    const float* __restrict__ bnp, float* __restrict__ hout, float* __restrict__ xsum)
{
    __shared__ float red[16][64];
    int t = threadIdx.x;
    int w = t >> 6;
    int l = t & 63;
    int c4 = (l & 15) * 4;
    int r = l >> 4;
    int n = blockIdx.x;

    float4 sB = *(const float4*)(bnp + c4);
    float4 hB = *(const float4*)(bnp + 64 + c4);
    float4 sS = *(const float4*)(bnp + 128 + c4);
    float4 hS = *(const float4*)(bnp + 192 + c4);
    float4 b2 = *(const float4*)(h2 + n * 64 + c4);
    float bx = b2.x * sS.x + hS.x;
    float by = b2.y * sS.y + hS.y;
    float bz = b2.z * sS.z + hS.z;
    float bw = b2.w * sS.w + hS.w;

    float4 acc = make_float4(0.f, 0.f, 0.f, 0.f);
    #pragma unroll
    for (int j = 0; j < 8; j++) {
        int si = w * 32 + j * 4 + r;
        size_t base = (size_t)(si * 512 + n) * 64 + c4;
        float4 a = *(const float4*)(h1 + base);
        float4 v;
        v.x = fmaxf(a.x * sB.x + hB.x + bx, 0.f);
        v.y = fmaxf(a.y * sB.y + hB.y + by, 0.f);
        v.z = fmaxf(a.z * sB.z + hB.z + bz, 0.f);
        v.w = fmaxf(a.w * sB.w + hB.w + bw, 0.f);
        *(float4*)(hout + base) = v;
        acc.x += v.x; acc.y += v.y; acc.z += v.z; acc.w += v.w;
    }
    acc.x += __shfl_xor(acc.x, 16, 64); acc.y += __shfl_xor(acc.y, 16, 64);
    acc.z += __shfl_xor(acc.z, 16, 64); acc.w += __shfl_xor(acc.w, 16, 64);
    acc.x += __shfl_xor(acc.x, 32, 64); acc.y += __shfl_xor(acc.y, 32, 64);
    acc.z += __shfl_xor(acc.z, 32, 64); acc.w += __shfl_xor(acc.w, 32, 64);
    if (l < 16) {
        red[w][c4 + 0] = acc.x;
        red[w][c4 + 1] = acc.y;
        red[w][c4 + 2] = acc.z;
        red[w][c4 + 3] = acc.w;
    }
    __syncthreads();
    if (t < 64) {
        float tot = 0.f;
        #pragma unroll
        for (int ww = 0; ww < 16; ww++) tot += red[ww][t];
        xsum[n * 64 + t] = tot * (1.f / 512.f);
    }
}

// ---------------- head ----------------
__global__ void head_kernel(const float* __restrict__ xs, const float* __restrict__ W1,
                            const float* __restrict__ b1, const float* __restrict__ W2,
                            const float* __restrict__ b2, float* __restrict__ out) {
    __shared__ float z[64];
    __shared__ float hid[128];
    int t = threadIdx.x;
    int n = blockIdx.x;
    if (t < 64) {
        float v = xs[n * 64 + t];
        float m = v;
        for (int off = 32; off >= 1; off >>= 1) m = fmaxf(m, __shfl_xor(m, off, 64));
        float e = expf(v - m);
        float s = e;
        for (int off = 32; off >= 1; off >>= 1) s += __shfl_xor(s, off, 64);
        z[t] = v - m - logf(s);
    }
    __syncthreads();
    {
        float acc = b1[t];
        const float* wrow = W1 + t * 64;
        #pragma unroll 8
        for (int k = 0; k < 64; k++) acc += z[k] * wrow[k];
        hid[t] = fmaxf(acc, 0.f);
    }
    __syncthreads();
    if (t < 10) {
        float o = b2[t];
        const float* wrow = W2 + t * 128;
        #pragma unroll 8
        for (int j = 0; j < 128; j++) o += hid[j] * wrow[j];
        out[n * 10 + t] = o;
    }
}

extern "C" void kernel_launch(void* const* d_in, const int* in_sizes, int n_in,
                              void* d_out, int out_size, void* d_ws, size_t ws_size,
                              hipStream_t stream) {
    const float* x       = (const float*)d_in[0];
    const float* Wrel    = (const float*)d_in[1];
    const float* brel    = (const float*)d_in[2];
    const float* Wroot   = (const float*)d_in[3];
    const float* bn_g    = (const float*)d_in[4];
    const float* bn_b    = (const float*)d_in[5];
    const float* Wrel_s  = (const float*)d_in[6];
    const float* brel_s  = (const float*)d_in[7];
    const float* Wroot_s = (const float*)d_in[8];
    const float* bns_g   = (const float*)d_in[9];
    const float* bns_b   = (const float*)d_in[10];
    const float* W1      = (const float*)d_in[11];
    const float* b1      = (const float*)d_in[12];
    const float* W2      = (const float*)d_in[13];
    const float* b2      = (const float*)d_in[14];
    const int* ei        = (const int*)d_in[15];
    const int* oei       = (const int*)d_in[16];
    float* out = (float*)d_out;

    char* ws = (char*)d_ws;
    size_t off = 0;
    auto alloc = [&](size_t bytes) -> void* {
        void* p = ws + off;
        off = (off + bytes + 255) & ~(size_t)255;
        return p;
    };
    float* h     = (float*)alloc((size_t)NT * 64 * 4);
    float* h1    = (float*)alloc((size_t)NT * 64 * 4);
    float* xsum  = (float*)alloc(NS * 64 * 4);
    float* h2    = (float*)alloc(NS * 64 * 4);
    float* stats = (float*)alloc(NLAYER * 2 * 4096 * 4);
    float* bnp   = (float*)alloc(256 * 4);
    int* bcnt    = (int*)alloc(NB * 4);
    int* bptr    = (int*)alloc((NB + 1) * 4);
    int* bcur    = (int*)alloc(NB * 4);
    unsigned short* ebuf = (unsigned short*)alloc((size_t)ES * 2);
    int* rowptrS = (int*)alloc(513 * 4);
    int* srcsS   = (int*)alloc(EO * 4);
    (void)ws_size; (void)in_sizes; (void)n_in; (void)out_size;

    hipMemsetAsync(bcnt, 0, NB * 4, stream);
    hipMemsetAsync(stats, 0, (size_t)NLAYER * 2 * 4096 * 4, stream);

    hist_bucket_kernel<<<ES / 256, 256, 0, stream>>>(ei + ES, bcnt);
    scan_bucket_kernel<<<1, 1024, 0, stream>>>(bcnt, bptr, bcur);
    scatter_bucket_kernel<<<ES / 256, 256, 0, stream>>>(ei, bcur, ebuf);
    small_csr_kernel<<<1, 1024, 0, stream>>>(oei, rowptrS, srcsS);

    smean_kernel<<<NS, 1024, 0, stream>>>(x, xsum);   // xsum of layer-0 input

    for (int i = 0; i < NLAYER; i++) {
        const float* hin = (i == 0) ? x : h;
        float* stB = stats + i * 8192;
        float* stS = stB + 4096;
        gconv_mfma_kernel<<<NT / 64, 256, 0, stream>>>(hin, bptr, ebuf,
            Wrel + i * 4096, Wroot + i * 4096, brel + i * 64, h1, stB);
        gconv_kernel<<<NS / 32, 512, 0, stream>>>(xsum, rowptrS, srcsS,
            Wrel_s + i * 4096, Wroot_s + i * 4096, brel_s + i * 64, h2, stS);
        finalize_kernel<<<1, 64, 0, stream>>>(stB, stS, bn_g + i * 64, bn_b + i * 64,
                                              bns_g + i * 64, bns_b + i * 64, bnp);
        combine_smean_kernel<<<NS, 1024, 0, stream>>>(h1, h2, bnp, h, xsum);
    }
    head_kernel<<<NS, 128, 0, stream>>>(xsum, W1, b1, W2, b2, out);
}

// Round 6
// 929.029 us; speedup vs baseline: 3.6893x; 1.0709x over previous
//
#include <hip/hip_runtime.h>
#include <math.h>

#define NT 262144
#define NS 512
#define ES 2097152
#define EO 8192
#define NLAYER 4
#define CHUNK 256       // per-wave LDS edge-stage chunk
#define EPB 4096        // edges per scatter/hist block-chunk

typedef short bf16x8 __attribute__((ext_vector_type(8)));
typedef float f32x16 __attribute__((ext_vector_type(16)));

__device__ inline unsigned short rne_bf16(float f) {
    unsigned int u = __float_as_uint(f);
    u += 0x7FFF + ((u >> 16) & 1);
    return (unsigned short)(u >> 16);
}

// ---------------- per-node CSR build, XCD-partitioned ----------------
// group g = blockIdx&7 handles only edges with (dst>>9)&7 == g, so every
// deg/cursor/ebuf cache line is touched by ONE XCD (under the same blockIdx->XCD
// round-robin the gconv swizzle exploits; wrong mapping = slower, never wrong).
__global__ void hist_xcd_kernel(const int* __restrict__ dst, int* __restrict__ deg) {
    int p = blockIdx.x;
    int g = p & 7;
    int base = (p >> 3) * EPB;
    for (int i = threadIdx.x; i < EPB; i += 256) {
        int d = dst[base + i];
        if (((d >> 9) & 7) == g) atomicAdd(&deg[d], 1);
    }
}

__global__ void scan1_kernel(const int* __restrict__ deg, int* __restrict__ rowptr,
                             int* __restrict__ bsum) {
    __shared__ int lds[1024];
    int t = threadIdx.x;
    int g = blockIdx.x * 1024 + t;
    int v = deg[g];
    lds[t] = v;
    __syncthreads();
    for (int off = 1; off < 1024; off <<= 1) {
        int x = (t >= off) ? lds[t - off] : 0;
        __syncthreads();
        lds[t] += x;
        __syncthreads();
    }
    rowptr[g] = lds[t] - v;
    if (t == 1023) bsum[blockIdx.x] = lds[t];
}

__global__ void scan2_kernel(int* bsum) {
    __shared__ int lds[256];
    int t = threadIdx.x;
    int v = bsum[t];
    lds[t] = v;
    __syncthreads();
    for (int off = 1; off < 256; off <<= 1) {
        int x = (t >= off) ? lds[t - off] : 0;
        __syncthreads();
        lds[t] += x;
        __syncthreads();
    }
    bsum[t] = lds[t] - v;
}

__global__ void scan3_kernel(int* __restrict__ rowptr, const int* __restrict__ bsum,
                             int* __restrict__ cursor) {
    int t = threadIdx.x;
    int g = blockIdx.x * 1024 + t;
    int v = rowptr[g] + bsum[blockIdx.x];
    rowptr[g] = v;
    cursor[g] = v;
    if (g == NT - 1) rowptr[NT] = ES;
}

__global__ void scatter_xcd_kernel(const int* __restrict__ ei, int* __restrict__ cur,
                                   unsigned short* __restrict__ ebuf) {
    int p = blockIdx.x;
    int g = p & 7;
    int base = (p >> 3) * EPB;
    for (int i = threadIdx.x; i < EPB; i += 256) {
        int d = ei[ES + base + i];
        if (((d >> 9) & 7) == g) {
            int s = ei[base + i];
            int pos = atomicAdd(&cur[d], 1);
            ebuf[pos] = (unsigned short)((s & 511) | ((d & 63) << 9));
        }
    }
}

// ---------------- CSR build (small graph, single block) ----------------
__global__ void small_csr_kernel(const int* __restrict__ oei, int* __restrict__ rowptrS,
                                 int* __restrict__ srcsS) {
    __shared__ int sdeg[NS];
    __shared__ int scur[NS];
    int t = threadIdx.x;
    if (t < NS) sdeg[t] = 0;
    __syncthreads();
    for (int e = t; e < EO; e += 1024) atomicAdd(&sdeg[oei[EO + e]], 1);
    __syncthreads();
    int myv = (t < NS) ? sdeg[t] : 0;
    __syncthreads();
    for (int off = 1; off < NS; off <<= 1) {
        int x = (t >= off && t < NS) ? sdeg[t - off] : 0;
        __syncthreads();
        if (t < NS) sdeg[t] += x;
        __syncthreads();
    }
    if (t < NS) {
        int excl = sdeg[t] - myv;
        rowptrS[t] = excl;
        scur[t] = excl;
        if (t == 0) rowptrS[NS] = EO;
    }
    __syncthreads();
    for (int e = t; e < EO; e += 1024) {
        int d = oei[EO + e];
        int pos = atomicAdd(&scur[d], 1);
        srcsS[pos] = oei[e];
    }
}

// ---------------- MFMA gconv: dst-sorted run-accumulating gather ----------
// Block = one 64-node tile (XCD swizzle: subgraph's 8 tiles on one XCD, gather
// L2-resident — verified R3). Wave w owns rows [w*16,w*16+16); its edge range
// is rowptr[row0]..rowptr[row0+16], records sorted by dst row, so aggregation
// runs in a register and each row is flushed to LDS exactly once.
__global__ __launch_bounds__(256, 4) void gconv_mfma_kernel(
    const float* __restrict__ hin, const int* __restrict__ rowptr,
    const unsigned short* __restrict__ ebuf,
    const float* __restrict__ Wr, const float* __restrict__ Wt, const float* __restrict__ br,
    float* __restrict__ hout, float* __restrict__ stats)
{
    __shared__ float agg[64 * 68];                 // 17.4 KB
    __shared__ unsigned short erec[4 * CHUNK];     // 2 KB

    int p = blockIdx.x;
    int xx = p & 7;
    int q = p >> 3;
    int sub = xx + 8 * (q >> 3);
    int tile = q & 7;
    int nb = (sub * 8 + tile) * 64;

    int tid = threadIdx.x;
    int w = tid >> 6;
    int l = tid & 63;

    for (int i = tid; i < 64 * 68; i += 256) agg[i] = 0.f;
    __syncthreads();

    // ---- gather ----
    int row0 = nb + w * 16;
    int q0 = rowptr[row0], q1 = rowptr[row0 + 16];
    const float* hsub = hin + (size_t)sub * 512 * 64;
    unsigned short* myrec = erec + w * CHUNK;
    float* aggw = agg + l;
    float accv = 0.f;
    int cur = w * 16;
    for (int base = q0; base < q1; base += CHUNK) {
        int cnt = min(q1 - base, CHUNK);
        for (int i = l; i < cnt; i += 64) myrec[i] = ebuf[base + i];
        __builtin_amdgcn_wave_barrier();
        int j = 0;
        for (; j + 4 <= cnt; j += 4) {
            uint2 rr = *(const uint2*)(myrec + j);   // uniform ds_read_b64
            unsigned a0 = rr.x & 0xffffu, a1 = rr.x >> 16;
            unsigned a2 = rr.y & 0xffffu, a3 = rr.y >> 16;
            int d0 = a0 >> 9, d1 = a1 >> 9, d2 = a2 >> 9, d3 = a3 >> 9;
            float v0 = hsub[(a0 & 511) * 64 + l];
            float v1 = hsub[(a1 & 511) * 64 + l];
            float v2 = hsub[(a2 & 511) * 64 + l];
            float v3 = hsub[(a3 & 511) * 64 + l];
            if (((d0 | d1 | d2 | d3) == (d0 & d1 & d2 & d3)) && d0 == cur) {
                accv += (v0 + v1) + (v2 + v3);       // fast path: run continues
            } else {
                if (d0 != cur) { aggw[cur * 68] = accv; accv = 0.f; cur = d0; }
                accv += v0;
                if (d1 != cur) { aggw[cur * 68] = accv; accv = 0.f; cur = d1; }
                accv += v1;
                if (d2 != cur) { aggw[cur * 68] = accv; accv = 0.f; cur = d2; }
                accv += v2;
                if (d3 != cur) { aggw[cur * 68] = accv; accv = 0.f; cur = d3; }
                accv += v3;
            }
        }
        for (; j < cnt; j++) {
            unsigned rec = myrec[j];
            int d = rec >> 9;
            float v = hsub[(rec & 511) * 64 + l];
            if (d != cur) { aggw[cur * 68] = accv; accv = 0.f; cur = d; }
            accv += v;
        }
        __builtin_amdgcn_wave_barrier();
    }
    aggw[cur * 68] = accv;   // final flush (rows with no edges keep their 0)

    // ---- B fragments ----
    int nt = w >> 1;
    int ct = w & 1;
    int n_out = ct * 32 + (l & 31);
    int kh = l >> 5;

    bf16x8 Bh[8], Bl[8];
    #pragma unroll
    for (int kc = 0; kc < 8; kc++) {
        int kbase = kc * 16 + kh * 8;
        const float* wsrc = (kbase < 64) ? (Wr + n_out * 64 + kbase)
                                         : (Wt + n_out * 64 + (kbase - 64));
        float4 u0 = *(const float4*)(wsrc);
        float4 u1 = *(const float4*)(wsrc + 4);
        float vv[8] = {u0.x, u0.y, u0.z, u0.w, u1.x, u1.y, u1.z, u1.w};
        #pragma unroll
        for (int j = 0; j < 8; j++) {
            unsigned short hi = rne_bf16(vv[j]);
            float hif = __uint_as_float((unsigned int)hi << 16);
            Bh[kc][j] = (short)hi;
            Bl[kc][j] = (short)rne_bf16(vv[j] - hif);
        }
    }
    float bias = br[n_out];
    __syncthreads();

    // ---- MFMA: A = [agg | h], split-bf16 (hh, lh, hl) ----
    f32x16 acc;
    #pragma unroll
    for (int j = 0; j < 16; j++) acc[j] = bias;

    int row = nt * 32 + (l & 31);
    const float* hrow = hin + (size_t)(nb + row) * 64;
    #pragma unroll
    for (int kc = 0; kc < 8; kc++) {
        int k0 = kc * 16 + kh * 8;
        float vv[8];
        if (kc < 4) {
            float4 a0 = *(const float4*)(agg + row * 68 + k0);
            float4 a1 = *(const float4*)(agg + row * 68 + k0 + 4);
            vv[0]=a0.x; vv[1]=a0.y; vv[2]=a0.z; vv[3]=a0.w;
            vv[4]=a1.x; vv[5]=a1.y; vv[6]=a1.z; vv[7]=a1.w;
        } else {
            float4 a0 = *(const float4*)(hrow + k0 - 64);
            float4 a1 = *(const float4*)(hrow + k0 - 60);
            vv[0]=a0.x; vv[1]=a0.y; vv[2]=a0.z; vv[3]=a0.w;
            vv[4]=a1.x; vv[5]=a1.y; vv[6]=a1.z; vv[7]=a1.w;
        }
        bf16x8 ah, al;
        #pragma unroll
        for (int j = 0; j < 8; j++) {
            unsigned short hi = rne_bf16(vv[j]);
            float hif = __uint_as_float((unsigned int)hi << 16);
            ah[j] = (short)hi;
            al[j] = (short)rne_bf16(vv[j] - hif);
        }
        acc = __builtin_amdgcn_mfma_f32_32x32x16_bf16(ah, Bh[kc], acc, 0, 0, 0);
        acc = __builtin_amdgcn_mfma_f32_32x32x16_bf16(al, Bh[kc], acc, 0, 0, 0);
        acc = __builtin_amdgcn_mfma_f32_32x32x16_bf16(ah, Bl[kc], acc, 0, 0, 0);
    }

    // ---- epilogue: store h1 + BN stats ----
    float s = 0.f, qv = 0.f;
    #pragma unroll
    for (int j = 0; j < 16; j++) {
        int crow = (j & 3) + 8 * (j >> 2) + 4 * (l >> 5);
        int node = nb + nt * 32 + crow;
        float v = acc[j];
        hout[node * 64 + n_out] = v;
        s += v;
        qv += v * v;
    }
    s += __shfl_xor(s, 32, 64);
    qv += __shfl_xor(qv, 32, 64);
    int rep = p & 31;
    if ((l & 32) == 0) {
        atomicAdd(&stats[rep * 128 + n_out], s);
        atomicAdd(&stats[rep * 128 + 64 + n_out], qv);
    }
}

// ---------------- VALU gconv (512-node small graph) ----------
__global__ __launch_bounds__(512, 6) void gconv_kernel(
    const float* __restrict__ hin, const int* __restrict__ rowptr, const int* __restrict__ srcs,
    const float* __restrict__ Wr, const float* __restrict__ Wt, const float* __restrict__ br,
    float* __restrict__ hout, float* __restrict__ stats)
{
    __shared__ float wrt[4096];
    __shared__ float wtt[4096];
    __shared__ float4 aggT[8][64];
    __shared__ float4 hT[8][64];
    __shared__ float sbuf[8][64];
    __shared__ float qbuf[8][64];
    __shared__ float brs[64];

    int tid = threadIdx.x;
    for (int idx = tid; idx < 4096; idx += 512) {
        int cc = idx >> 6, kk = idx & 63;
        wrt[kk * 64 + ((kk + cc) & 63)] = Wr[idx];
        wtt[kk * 64 + ((kk + cc) & 63)] = Wt[idx];
    }
    if (tid < 64) brs[tid] = br[tid];
    __syncthreads();

    int w = tid >> 6;
    int c = tid & 63;
    int node0 = (blockIdx.x * 8 + w) * 4;

    float* aggp = (float*)&aggT[w][0];
    float* hp   = (float*)&hT[w][0];
    #pragma unroll
    for (int r = 0; r < 4; r++) {
        int node = node0 + r;
        hp[c * 4 + r] = hin[node * 64 + c];
        int e0 = rowptr[node], e1 = rowptr[node + 1];
        float a = 0.f;
        int e = e0;
        for (; e + 4 <= e1; e += 4) {
            int s0 = srcs[e], s1 = srcs[e + 1], s2 = srcs[e + 2], s3 = srcs[e + 3];
            float v0 = hin[s0 * 64 + c];
            float v1 = hin[s1 * 64 + c];
            float v2 = hin[s2 * 64 + c];
            float v3 = hin[s3 * 64 + c];
            a += (v0 + v1) + (v2 + v3);
        }
        for (; e < e1; e++) a += hin[srcs[e] * 64 + c];
        aggp[c * 4 + r] = a;
    }

    float o0 = brs[c], o1 = o0, o2 = o0, o3 = o0;
    #pragma unroll 8
    for (int k = 0; k < 64; k++) {
        float wr = wrt[k * 64 + ((k + c) & 63)];
        float wt = wtt[k * 64 + ((k + c) & 63)];
        float4 av = aggT[w][k];
        float4 hv = hT[w][k];
        o0 += wr * av.x + wt * hv.x;
        o1 += wr * av.y + wt * hv.y;
        o2 += wr * av.z + wt * hv.z;
        o3 += wr * av.w + wt * hv.w;
    }
    hout[(node0 + 0) * 64 + c] = o0;
    hout[(node0 + 1) * 64 + c] = o1;
    hout[(node0 + 2) * 64 + c] = o2;
    hout[(node0 + 3) * 64 + c] = o3;

    sbuf[w][c] = (o0 + o1) + (o2 + o3);
    qbuf[w][c] = (o0 * o0 + o1 * o1) + (o2 * o2 + o3 * o3);
    __syncthreads();
    int rep = blockIdx.x & 31;
    if (w == 0) {
        float s = 0.f;
        #pragma unroll
        for (int ww = 0; ww < 8; ww++) s += sbuf[ww][c];
        atomicAdd(&stats[rep * 128 + c], s);
    } else if (w == 1) {
        float q = 0.f;
        #pragma unroll
        for (int ww = 0; ww < 8; ww++) q += qbuf[ww][c];
        atomicAdd(&stats[rep * 128 + 64 + c], q);
    }
}

// ---------------- subgraph mean (only for the initial x) ----------------
__global__ void smean_kernel(const float* __restrict__ hin, float* __restrict__ xsum) {
    __shared__ float red[16][64];
    int t = threadIdx.x;
    int w = t >> 6, c = t & 63;
    int n = blockIdx.x;
    int base = n * 64 + c;
    float s = 0.f;
    #pragma unroll 8
    for (int j = 0; j < 32; j++) {
        int si = w * 32 + j;
        s += hin[si * 32768 + base];
    }
    red[w][c] = s;
    __syncthreads();
    if (w == 0) {
        float tot = 0.f;
        #pragma unroll
        for (int ww = 0; ww < 16; ww++) tot += red[ww][c];
        xsum[base] = tot * (1.f / 512.f);
    }
}

// ---- h = relu(bn(h1)+bn(h2)[n]) + next-layer smean, BN-finalize fused ----
__global__ __launch_bounds__(1024) void combine_smean_kernel(
    const float* __restrict__ h1, const float* __restrict__ h2,
    const float* __restrict__ stB, const float* __restrict__ stS,
    const float* __restrict__ gB, const float* __restrict__ bB,
    const float* __restrict__ gS, const float* __restrict__ bS,
    float* __restrict__ hout, float* __restrict__ xsum)
{
    __shared__ float bnp[256];
    __shared__ float red[16][64];
    int t = threadIdx.x;
    if (t < 64) {
        int c = t;
        float sb = 0.f, qb = 0.f, ss = 0.f, qs = 0.f;
        for (int r2 = 0; r2 < 32; r2++) {
            sb += stB[r2 * 128 + c];
            qb += stB[r2 * 128 + 64 + c];
            ss += stS[r2 * 128 + c];
            qs += stS[r2 * 128 + 64 + c];
        }
        float muB = sb * (1.f / 262144.f);
        float varB = qb * (1.f / 262144.f) - muB * muB;
        float scB = gB[c] * rsqrtf(varB + 1e-5f);
        bnp[c] = scB;
        bnp[64 + c] = bB[c] - muB * scB;
        float muS = ss * (1.f / 512.f);
        float varS = qs * (1.f / 512.f) - muS * muS;
        float scS = gS[c] * rsqrtf(varS + 1e-5f);
        bnp[128 + c] = scS;
        bnp[192 + c] = bS[c] - muS * scS;
    }
    __syncthreads();

    int w = t >> 6;
    int l = t & 63;
    int c4 = (l & 15) * 4;
    int r = l >> 4;
    int n = blockIdx.x;

    float4 sB = *(const float4*)(bnp + c4);
    float4 hB = *(const float4*)(bnp + 64 + c4);
    float4 sS = *(const float4*)(bnp + 128 + c4);
    float4 hS = *(const float4*)(bnp + 192 + c4);
    float4 b2 = *(const float4*)(h2 + n * 64 + c4);
    float bx = b2.x * sS.x + hS.x;
    float by = b2.y * sS.y + hS.y;
    float bz = b2.z * sS.z + hS.z;
    float bw = b2.w * sS.w + hS.w;

    float4 acc = make_float4(0.f, 0.f, 0.f, 0.f);
    #pragma unroll
    for (int j = 0; j < 8; j++) {
        int si = w * 32 + j * 4 + r;
        size_t base = (size_t)(si * 512 + n) * 64 + c4;
        float4 a = *(const float4*)(h1 + base);
        float4 v;
        v.x = fmaxf(a.x * sB.x + hB.x + bx, 0.f);
        v.y = fmaxf(a.y * sB.y + hB.y + by, 0.f);
        v.z = fmaxf(a.z * sB.z + hB.z + bz, 0.f);
        v.w = fmaxf(a.w * sB.w + hB.w + bw, 0.f);
        *(float4*)(hout + base) = v;
        acc.x += v.x; acc.y += v.y; acc.z += v.z; acc.w += v.w;
    }
    acc.x += __shfl_xor(acc.x, 16, 64); acc.y += __shfl_xor(acc.y, 16, 64);
    acc.z += __shfl_xor(acc.z, 16, 64); acc.w += __shfl_xor(acc.w, 16, 64);
    acc.x += __shfl_xor(acc.x, 32, 64); acc.y += __shfl_xor(acc.y, 32, 64);
    acc.z += __shfl_xor(acc.z, 32, 64); acc.w += __shfl_xor(acc.w, 32, 64);
    if (l < 16) {
        red[w][c4 + 0] = acc.x;
        red[w][c4 + 1] = acc.y;
        red[w][c4 + 2] = acc.z;
        red[w][c4 + 3] = acc.w;
    }
    __syncthreads();
    if (t < 64) {
        float tot = 0.f;
        #pragma unroll
        for (int ww = 0; ww < 16; ww++) tot += red[ww][t];
        xsum[n * 64 + t] = tot * (1.f / 512.f);
    }
}

// ---------------- head ----------------
__global__ void head_kernel(const float* __restrict__ xs, const float* __restrict__ W1,
                            const float* __restrict__ b1, const float* __restrict__ W2,
                            const float* __restrict__ b2, float* __restrict__ out) {
    __shared__ float z[64];
    __shared__ float hid[128];
    int t = threadIdx.x;
    int n = blockIdx.x;
    if (t < 64) {
        float v = xs[n * 64 + t];
        float m = v;
        for (int off = 32; off >= 1; off >>= 1) m = fmaxf(m, __shfl_xor(m, off, 64));
        float e = expf(v - m);
        float s = e;
        for (int off = 32; off >= 1; off >>= 1) s += __shfl_xor(s, off, 64);
        z[t] = v - m - logf(s);
    }
    __syncthreads();
    {
        float acc = b1[t];
        const float* wrow = W1 + t * 64;
        #pragma unroll 8
        for (int k = 0; k < 64; k++) acc += z[k] * wrow[k];
        hid[t] = fmaxf(acc, 0.f);
    }
    __syncthreads();
    if (t < 10) {
        float o = b2[t];
        const float* wrow = W2 + t * 128;
        #pragma unroll 8
        for (int j = 0; j < 128; j++) o += hid[j] * wrow[j];
        out[n * 10 + t] = o;
    }
}

extern "C" void kernel_launch(void* const* d_in, const int* in_sizes, int n_in,
                              void* d_out, int out_size, void* d_ws, size_t ws_size,
                              hipStream_t stream) {
    const float* x       = (const float*)d_in[0];
    const float* Wrel    = (const float*)d_in[1];
    const float* brel    = (const float*)d_in[2];
    const float* Wroot   = (const float*)d_in[3];
    const float* bn_g    = (const float*)d_in[4];
    const float* bn_b    = (const float*)d_in[5];
    const float* Wrel_s  = (const float*)d_in[6];
    const float* brel_s  = (const float*)d_in[7];
    const float* Wroot_s = (const float*)d_in[8];
    const float* bns_g   = (const float*)d_in[9];
    const float* bns_b   = (const float*)d_in[10];
    const float* W1      = (const float*)d_in[11];
    const float* b1      = (const float*)d_in[12];
    const float* W2      = (const float*)d_in[13];
    const float* b2      = (const float*)d_in[14];
    const int* ei        = (const int*)d_in[15];
    const int* oei       = (const int*)d_in[16];
    float* out = (float*)d_out;

    char* ws = (char*)d_ws;
    size_t off = 0;
    auto alloc = [&](size_t bytes) -> void* {
        void* p = ws + off;
        off = (off + bytes + 255) & ~(size_t)255;
        return p;
    };
    float* h     = (float*)alloc((size_t)NT * 64 * 4);
    float* h1    = (float*)alloc((size_t)NT * 64 * 4);
    float* xsum  = (float*)alloc(NS * 64 * 4);
    float* h2    = (float*)alloc(NS * 64 * 4);
    float* stats = (float*)alloc(NLAYER * 2 * 4096 * 4);
    int* deg     = (int*)alloc((size_t)NT * 4);
    int* rowptr  = (int*)alloc((size_t)(NT + 1) * 4);
    int* cursor  = (int*)alloc((size_t)NT * 4);
    int* bsum    = (int*)alloc(256 * 4);
    unsigned short* ebuf = (unsigned short*)alloc((size_t)ES * 2);
    int* rowptrS = (int*)alloc(513 * 4);
    int* srcsS   = (int*)alloc(EO * 4);
    (void)ws_size; (void)in_sizes; (void)n_in; (void)out_size;

    hipMemsetAsync(deg, 0, (size_t)NT * 4, stream);
    hipMemsetAsync(stats, 0, (size_t)NLAYER * 2 * 4096 * 4, stream);

    hist_xcd_kernel<<<ES / EPB * 8, 256, 0, stream>>>(ei + ES, deg);
    scan1_kernel<<<NT / 1024, 1024, 0, stream>>>(deg, rowptr, bsum);
    scan2_kernel<<<1, 256, 0, stream>>>(bsum);
    scan3_kernel<<<NT / 1024, 1024, 0, stream>>>(rowptr, bsum, cursor);
    scatter_xcd_kernel<<<ES / EPB * 8, 256, 0, stream>>>(ei, cursor, ebuf);
    small_csr_kernel<<<1, 1024, 0, stream>>>(oei, rowptrS, srcsS);

    smean_kernel<<<NS, 1024, 0, stream>>>(x, xsum);   // xsum of layer-0 input

    for (int i = 0; i < NLAYER; i++) {
        const float* hin = (i == 0) ? x : h;
        float* stB = stats + i * 8192;
        float* stS = stB + 4096;
        gconv_mfma_kernel<<<NT / 64, 256, 0, stream>>>(hin, rowptr, ebuf,
            Wrel + i * 4096, Wroot + i * 4096, brel + i * 64, h1, stB);
        gconv_kernel<<<NS / 32, 512, 0, stream>>>(xsum, rowptrS, srcsS,
            Wrel_s + i * 4096, Wroot_s + i * 4096, brel_s + i * 64, h2, stS);
        combine_smean_kernel<<<NS, 1024, 0, stream>>>(h1, h2, stB, stS,
            bn_g + i * 64, bn_b + i * 64, bns_g + i * 64, bns_b + i * 64, h, xsum);
    }
    head_kernel<<<NS, 128, 0, stream>>>(xsum, W1, b1, W2, b2, out);
}